// Round 5
// baseline (153.069 us; speedup 1.0000x reference)
//
#include <hip/hip_runtime.h>

#define NB 8
#define CC 256
#define HH 8
#define DD 32
#define LL 4096

typedef short v8s __attribute__((ext_vector_type(8)));
typedef float v4f __attribute__((ext_vector_type(4)));
typedef unsigned short v8u __attribute__((ext_vector_type(8)));
typedef unsigned short v4us __attribute__((ext_vector_type(4)));

__device__ __forceinline__ float4 ld4(const float* p) { return *(const float4*)p; }

// round-to-nearest-even fp32 -> bf16 (as ushort)
__device__ __forceinline__ unsigned short f2bf(float f) {
    union { float f; unsigned int u; } v; v.f = f;
    unsigned int r = (v.u + 0x7FFFu + ((v.u >> 16) & 1u)) >> 16;
    return (unsigned short)r;
}
__device__ __forceinline__ float bf2f(unsigned short u) {
    union { unsigned int u; float f; } v; v.u = ((unsigned int)u) << 16;
    return v.f;
}

// async global->LDS, 16 B per lane (dest = wave-uniform base + lane*16)
__device__ __forceinline__ void gl_lds16(const unsigned short* g, unsigned short* l) {
    __builtin_amdgcn_global_load_lds(
        (const __attribute__((address_space(1))) void*)g,
        (__attribute__((address_space(3))) void*)l, 16, 0, 0);
}

// ---------------------------------------------------------------------------
// prep_w: weights fp32 -> bf16 (verbatim).  128 blocks.
// ---------------------------------------------------------------------------
__global__ __launch_bounds__(256) void prep_w(
    const float* __restrict__ wq, const float* __restrict__ wp,
    unsigned short* __restrict__ dwq, unsigned short* __restrict__ dwp)
{
    int ti = blockIdx.x * 256 + threadIdx.x;
    if (ti < 24576) {                       // 3*CC*CC / 8
        int i = ti * 8;
        float4 f0 = ld4(wq + i), f1 = ld4(wq + i + 4);
        v8u o;
        o[0] = f2bf(f0.x); o[1] = f2bf(f0.y); o[2] = f2bf(f0.z); o[3] = f2bf(f0.w);
        o[4] = f2bf(f1.x); o[5] = f2bf(f1.y); o[6] = f2bf(f1.z); o[7] = f2bf(f1.w);
        *(v8u*)(dwq + i) = o;
    } else {                                // CC*CC / 8
        int i = (ti - 24576) * 8;
        float4 f0 = ld4(wp + i), f1 = ld4(wp + i + 4);
        v8u o;
        o[0] = f2bf(f0.x); o[1] = f2bf(f0.y); o[2] = f2bf(f0.z); o[3] = f2bf(f0.w);
        o[4] = f2bf(f1.x); o[5] = f2bf(f1.y); o[6] = f2bf(f1.z); o[7] = f2bf(f1.w);
        *(v8u*)(dwp + i) = o;
    }
}

// ---------------------------------------------------------------------------
// W half-tile prefetch: 256 j x 32 c into wbuf_b, pre-swizzled source so
// LDS holds chunk (pos ^ swzf(row)) at pos, swzf(row) = (row>>1)&3.
// Per thread: 4 issues x 16 rows (lane>>2) x chunk ((lane&3)^((lane>>3)&3)).
// ---------------------------------------------------------------------------
__device__ __forceinline__ void issue_w(
    const unsigned short* __restrict__ wqb, unsigned short* wbuf_b,
    int jt, int kt, int wave, int lane)
{
    const int wrow = lane >> 2;
    const int wsc  = (lane & 3) ^ ((lane >> 3) & 3);
    const unsigned short* wg = wqb + (size_t)(jt * 256 + wave * 64 + wrow) * CC
                             + kt * 32 + wsc * 8;
    unsigned short* wl = wbuf_b + wave * 2048 + lane * 8;
#pragma unroll
    for (int i = 0; i < 4; ++i)
        gl_lds16(wg + (size_t)i * 16 * CC, wl + i * 512);
}

// ---------------------------------------------------------------------------
// Kernel 1: qkv GEMM.  Block = one (64 l, n) tile; X transposed + staged ONCE
// (full K=256, 32 KB, XOR-swizzled).  24 phases (3 jt x 8 kt, K-step 32) with
// DOUBLE-BUFFERED W tiles: one barrier per phase; each barrier's vmcnt drain
// is covered by the previous phase's 16 MFMA + 8 ds_read + issue.
// Grid 512 = exactly 2 blocks/CU (LDS 64 KB).  Per-head L2 norm fused for q/k.
// Blocks < 256 also zero the attn accumulator (stream-ordered before attn_k).
// ---------------------------------------------------------------------------
__global__ __launch_bounds__(256, 2) void gemm_qkv_mfma(
    const float* __restrict__ x, const unsigned short* __restrict__ wqb,
    const float* __restrict__ bqkv,
    unsigned short* __restrict__ q, unsigned short* __restrict__ k,
    unsigned short* __restrict__ v, float* __restrict__ attn)
{
    __shared__ __align__(16) unsigned short xsf[16384];     // 64 l x 256 c (swz)
    __shared__ __align__(16) unsigned short wbuf[2][8192];  // 2 x (256 j x 32 c, swz)

    const int bid = blockIdx.x;
    const int l0 = (bid & 63) * 64;
    const int n  = bid >> 6;
    const int tid = threadIdx.x;
    const int lane = tid & 63, wave = tid >> 6;
    const int r = lane & 15, quad = lane >> 4;

    // prefetch first W half-tile ASAP
    issue_w(wqb, wbuf[0], 0, 0, wave, lane);

    // ---- stage X once: transpose-gather fp32 -> bf16, swizzled (verbatim) ----
    {
        const int lx = tid & 63, cq = tid >> 6;
        const float* xcol = x + (size_t)n * CC * LL + l0 + lx;
        unsigned short* xrow = xsf + lx * 256;
#pragma unroll
        for (int i = 0; i < 8; ++i) {
            const float* src = xcol + (size_t)(cq * 8 + i) * 8 * LL;
            float f[8];
#pragma unroll
            for (int j = 0; j < 8; ++j) f[j] = src[(size_t)j * LL];
            v8u o;
#pragma unroll
            for (int j = 0; j < 8; ++j) o[j] = f2bf(f[j]);
            *(v8u*)(xrow + (cq * 8 + (i ^ (lx & 7))) * 8) = o;
        }
    }

    if (bid < 256) attn[bid * 256 + tid] = 0.f;

    const int jbase = wave * 64;
    v4f acc[4][4];
#pragma unroll
    for (int mi = 0; mi < 4; ++mi)
#pragma unroll
        for (int nj = 0; nj < 4; ++nj) acc[mi][nj] = (v4f)(0.f);

    int cur = 0;
#pragma unroll
    for (int t = 0; t < 24; ++t) {
        __syncthreads();                 // W(t) ready; buf(cur^1) readers done
        if (t < 23)
            issue_w(wqb, wbuf[cur ^ 1], (t + 1) >> 3, (t + 1) & 7, wave, lane);

        const int kt = t & 7;
        const int pos = (kt >> 1) * 8 + ((((kt & 1) << 2) + quad) ^ (r & 7));
        v8s b[4];
#pragma unroll
        for (int nj = 0; nj < 4; ++nj)
            b[nj] = *(const v8s*)(xsf + (nj * 16 + r) * 256 + pos * 8);
        const int ws = (quad ^ ((r >> 1) & 3)) * 8;
        v8s a[4];
#pragma unroll
        for (int mi = 0; mi < 4; ++mi)
            a[mi] = *(const v8s*)(wbuf[cur] + (jbase + mi * 16 + r) * 32 + ws);
#pragma unroll
        for (int mi = 0; mi < 4; ++mi)
#pragma unroll
            for (int nj = 0; nj < 4; ++nj)
                acc[mi][nj] = __builtin_amdgcn_mfma_f32_16x16x32_bf16(
                    a[mi], b[nj], acc[mi][nj], 0, 0, 0);

        if ((t & 7) == 7) {
            // ---- epilogue for jt = t>>3 (verbatim round-4 math) ----
            const int jt = t >> 3;
            const int j0 = jt * 256;
            unsigned short* basep = (jt == 0 ? q : (jt == 1 ? k : v));
            float bias[4][4];
#pragma unroll
            for (int mi = 0; mi < 4; ++mi)
                *(float4*)bias[mi] = *(const float4*)(bqkv + j0 + jbase + mi * 16 + quad * 4);

            unsigned short* dstp[4];
#pragma unroll
            for (int mi = 0; mi < 4; ++mi) {
                int hh = wave * 2 + (mi >> 1);
                int d0 = (mi & 1) * 16 + quad * 4;
                dstp[mi] = basep + (size_t)(n * HH + hh) * LL * DD + d0;
            }

            if (jt < 2) {
#pragma unroll
                for (int nj = 0; nj < 4; ++nj) {
                    float t4[4][4];
                    float ss[2] = {0.f, 0.f};
#pragma unroll
                    for (int mi = 0; mi < 4; ++mi)
#pragma unroll
                        for (int reg = 0; reg < 4; ++reg) {
                            float val = acc[mi][nj][reg] + bias[mi][reg];
                            t4[mi][reg] = val;
                            ss[mi >> 1] += val * val;
                        }
#pragma unroll
                    for (int g2 = 0; g2 < 2; ++g2) {
                        ss[g2] += __shfl_xor(ss[g2], 16);
                        ss[g2] += __shfl_xor(ss[g2], 32);
                        ss[g2] = rsqrtf(ss[g2]);
                    }
                    size_t l = (size_t)(l0 + nj * 16 + r);
#pragma unroll
                    for (int mi = 0; mi < 4; ++mi) {
                        float rn = ss[mi >> 1];
                        v4us pk;
#pragma unroll
                        for (int reg = 0; reg < 4; ++reg) pk[reg] = f2bf(t4[mi][reg] * rn);
                        *(v4us*)(dstp[mi] + l * DD) = pk;
                    }
                }
            } else {
#pragma unroll
                for (int nj = 0; nj < 4; ++nj) {
                    size_t l = (size_t)(l0 + nj * 16 + r);
#pragma unroll
                    for (int mi = 0; mi < 4; ++mi) {
                        v4us pk;
#pragma unroll
                        for (int reg = 0; reg < 4; ++reg)
                            pk[reg] = f2bf(acc[mi][nj][reg] + bias[mi][reg]);
                        *(v4us*)(dstp[mi] + l * DD) = pk;
                    }
                }
            }
            // re-zero accumulator for next jt
#pragma unroll
            for (int mi = 0; mi < 4; ++mi)
#pragma unroll
                for (int nj = 0; nj < 4; ++nj) acc[mi][nj] = (v4f)(0.f);
        }
        cur ^= 1;
    }
}

// ---------------------------------------------------------------------------
// Kernel 3: attn[n,h,d,e] = sum_l k[n,h,l,d] * v[n,h,l,e]   (verbatim)
// ---------------------------------------------------------------------------
__global__ __launch_bounds__(256) void attn_k(
    const unsigned short* __restrict__ k, const unsigned short* __restrict__ v,
    float* __restrict__ attn)
{
    __shared__ float red[4][1024];
    const int nh = blockIdx.y;
    const int wv = threadIdx.x >> 6;
    const int lane = threadIdx.x & 63;
    const int eg = lane & 7;
    const int dg = lane >> 3;
    const int l0 = blockIdx.x * 512 + wv * 128;
    const unsigned short* kb = k + (size_t)nh * LL * DD;
    const unsigned short* vb = v + (size_t)nh * LL * DD;
    float acc[4][4] = {};
#pragma unroll 4
    for (int l = l0; l < l0 + 128; ++l) {
        v4us k4 = *(const v4us*)(kb + (size_t)l * DD + dg * 4);
        v4us v4 = *(const v4us*)(vb + (size_t)l * DD + eg * 4);
        float ka[4] = {bf2f(k4[0]), bf2f(k4[1]), bf2f(k4[2]), bf2f(k4[3])};
        float va[4] = {bf2f(v4[0]), bf2f(v4[1]), bf2f(v4[2]), bf2f(v4[3])};
#pragma unroll
        for (int dp = 0; dp < 4; ++dp)
#pragma unroll
            for (int ep = 0; ep < 4; ++ep)
                acc[dp][ep] += ka[dp] * va[ep];
    }
#pragma unroll
    for (int dp = 0; dp < 4; ++dp)
#pragma unroll
        for (int ep = 0; ep < 4; ++ep)
            red[wv][(dg * 4 + dp) * 32 + eg * 4 + ep] = acc[dp][ep];
    __syncthreads();
    float* ap = attn + (size_t)nh * 1024;
    for (int i = threadIdx.x; i < 1024; i += 256)
        atomicAdd(&ap[i], red[0][i] + red[1][i] + red[2][i] + red[3][i]);
}

// ---------------------------------------------------------------------------
// Kernel 4 (fused mid + proj): verbatim round-4.
// ---------------------------------------------------------------------------
#define PTOK 64
#define VTP 40
__global__ __launch_bounds__(256, 2) void midproj_k(
    const unsigned short* __restrict__ q, const unsigned short* __restrict__ v,
    const float* __restrict__ attn, const float* __restrict__ wd,
    const unsigned short* __restrict__ wpb, const float* __restrict__ bp,
    float* __restrict__ out)
{
    __shared__ __align__(16) unsigned short vt[8 * 72 * VTP];   // [h][row][40]
    __shared__ __align__(16) unsigned short smid[4 * 64 * 64];  // [chunk][l][64] swz

    const int n  = blockIdx.y;
    const int l0 = blockIdx.x * PTOK;
    const int tid = threadIdx.x;
    const int lane = tid & 63, wave = tid >> 6;
    const int r = lane & 15, quad = lane >> 4;

    // ---- stage v halo for all 8 heads ----
    const unsigned short* vbase = v + (size_t)(n * HH) * LL * DD;
#pragma unroll
    for (int it = 0; it < 9; ++it) {
        int task = it * 256 + tid;            // 2304 = 8h * 72rows * 4segs
        int seg = task & 3;
        int hr = task >> 2;                   // h*72 + row
        int row = hr % 72;
        int h = hr / 72;
        int l = l0 - 4 + row;
        v8u val;
        if (l >= 0 && l < LL)
            val = *(const v8u*)(vbase + ((size_t)h * LL + l) * DD + seg * 8);
        else
            val = (v8u)(unsigned short)0;
        *(v8u*)(&vt[hr * VTP + seg * 8]) = val;
    }
    __syncthreads();

    const float inv_pi = 0.31830988618379067f;
#pragma unroll
    for (int hi = 0; hi < 2; ++hi) {
        const int h = wave * 2 + hi;
        const int nh = n * HH + h;
        const unsigned short* qb = q + (size_t)nh * LL * DD;
        const unsigned short* vth = vt + h * 72 * VTP;

        v8s bfrag[2];
#pragma unroll
        for (int et = 0; et < 2; ++et) {
            int e = et * 16 + r;
#pragma unroll
            for (int j = 0; j < 8; ++j)
                ((unsigned short*)&bfrag[et])[j] =
                    f2bf(attn[(size_t)nh * 1024 + (quad * 8 + j) * 32 + e]);
        }
        float wc[9];
#pragma unroll
        for (int r9 = 0; r9 < 9; ++r9) wc[r9] = wd[h * 9 + r9];

#pragma unroll
        for (int lt = 0; lt < 4; ++lt) {
            const int tb = lt * 16;
            v8s afrag = *(const v8s*)(qb + (size_t)(l0 + tb + r) * DD + quad * 8);
            v4f acc[2] = {(v4f)(0.f), (v4f)(0.f)};
#pragma unroll
            for (int et = 0; et < 2; ++et)
                acc[et] = __builtin_amdgcn_mfma_f32_16x16x32_bf16(
                    afrag, bfrag[et], acc[et], 0, 0, 0);

            float vcol[2][12];
#pragma unroll
            for (int et = 0; et < 2; ++et) {
                int e = et * 16 + r;
#pragma unroll
                for (int o = 0; o < 12; ++o)
                    vcol[et][o] = bf2f(vth[(tb + quad * 4 + o) * VTP + e]);
            }

            float t[2][4], ss[4];
#pragma unroll
            for (int reg = 0; reg < 4; ++reg) {
                t[0][reg] = 0.5f * vcol[0][4 + reg] + inv_pi * acc[0][reg];
                t[1][reg] = 0.5f * vcol[1][4 + reg] + inv_pi * acc[1][reg];
                ss[reg] = t[0][reg] * t[0][reg] + t[1][reg] * t[1][reg];
            }
#pragma unroll
            for (int m = 1; m < 16; m <<= 1)
#pragma unroll
                for (int reg = 0; reg < 4; ++reg)
                    ss[reg] += __shfl_xor(ss[reg], m);
#pragma unroll
            for (int reg = 0; reg < 4; ++reg) ss[reg] = rsqrtf(ss[reg]);

#pragma unroll
            for (int et = 0; et < 2; ++et) {
                int c = h * 32 + et * 16 + r;
                int chunk = c >> 6, c6 = c & 63;
                int goff = c6 & 7;
#pragma unroll
                for (int reg = 0; reg < 4; ++reg) {
                    float dv = 0.f;
#pragma unroll
                    for (int r9 = 0; r9 < 9; ++r9) dv += wc[r9] * vcol[et][reg + r9];
                    int l = tb + quad * 4 + reg;
                    int g = (c6 >> 3) ^ (l & 7);
                    smid[chunk * 4096 + l * 64 + g * 8 + goff] =
                        f2bf(t[et][reg] * ss[reg] + dv);
                }
            }
        }
    }
    __syncthreads();

    // ---- proj phase (no barriers) ----
    const int jbase = wave * 64;
    v4f acc[4][4];
#pragma unroll
    for (int mi = 0; mi < 4; ++mi)
#pragma unroll
        for (int nj = 0; nj < 4; ++nj) acc[mi][nj] = (v4f)(0.f);

#pragma unroll
    for (int kt = 0; kt < 4; ++kt) {
        v8s a[4][2], b[4][2];
#pragma unroll
        for (int kk = 0; kk < 2; ++kk) {
            const int cfrag = kk * 4 + quad;
#pragma unroll
            for (int mi = 0; mi < 4; ++mi) {
                int j = jbase + mi * 16 + r;
                a[mi][kk] = *(const v8s*)(wpb + (size_t)j * CC + kt * 64 + cfrag * 8);
            }
            const int s = cfrag ^ (r & 7);
#pragma unroll
            for (int nj = 0; nj < 4; ++nj) {
                int lloc = nj * 16 + r;
                b[nj][kk] = *(const v8s*)(smid + kt * 4096 + lloc * 64 + s * 8);
            }
        }
#pragma unroll
        for (int kk = 0; kk < 2; ++kk)
#pragma unroll
            for (int mi = 0; mi < 4; ++mi)
#pragma unroll
                for (int nj = 0; nj < 4; ++nj)
                    acc[mi][nj] = __builtin_amdgcn_mfma_f32_16x16x32_bf16(
                        a[mi][kk], b[nj][kk], acc[mi][nj], 0, 0, 0);
    }

#pragma unroll
    for (int mi = 0; mi < 4; ++mi)
#pragma unroll
        for (int reg = 0; reg < 4; ++reg) {
            int j = jbase + mi * 16 + quad * 4 + reg;
            float bias = bp[j];
#pragma unroll
            for (int nj = 0; nj < 4; ++nj) {
                int l = l0 + nj * 16 + r;
                out[((size_t)n * CC + j) * LL + l] = acc[mi][nj][reg] + bias;
            }
        }
}

// ---------------------------------------------------------------------------
extern "C" void kernel_launch(void* const* d_in, const int* in_sizes, int n_in,
                              void* d_out, int out_size, void* d_ws, size_t ws_size,
                              hipStream_t stream)
{
    const float* x     = (const float*)d_in[0];
    const float* wqkv  = (const float*)d_in[1];
    const float* bqkv  = (const float*)d_in[2];
    const float* wproj = (const float*)d_in[3];
    const float* bproj = (const float*)d_in[4];
    const float* wd    = (const float*)d_in[5];
    float* out = (float*)d_out;

    const size_t QKV = (size_t)NB * HH * LL * DD;       // 8388608 elems
    unsigned short* q = (unsigned short*)d_ws;
    unsigned short* k = q + QKV;
    unsigned short* v = k + QKV;
    float* attn = (float*)(v + QKV);                    // 65536 floats
    unsigned short* wqb = (unsigned short*)(attn + (size_t)NB * HH * DD * DD);
    unsigned short* wpb = wqb + 3 * CC * CC;

    prep_w<<<128, 256, 0, stream>>>(wqkv, wproj, wqb, wpb);
    gemm_qkv_mfma<<<512, 256, 0, stream>>>(x, wqb, bqkv, q, k, v, attn);
    attn_k<<<dim3(8, 64), 256, 0, stream>>>(k, v, attn);
    midproj_k<<<dim3(LL / PTOK, NB), 256, 0, stream>>>(q, v, attn, wd, wpb, bproj, out);
}

// Round 6
// 149.651 us; speedup vs baseline: 1.0228x; 1.0228x over previous
//
#include <hip/hip_runtime.h>

#define NB 8
#define CC 256
#define HH 8
#define DD 32
#define LL 4096

typedef short v8s __attribute__((ext_vector_type(8)));
typedef float v4f __attribute__((ext_vector_type(4)));
typedef unsigned short v8u __attribute__((ext_vector_type(8)));
typedef unsigned short v4us __attribute__((ext_vector_type(4)));

__device__ __forceinline__ float4 ld4(const float* p) { return *(const float4*)p; }

// round-to-nearest-even fp32 -> bf16 (as ushort)
__device__ __forceinline__ unsigned short f2bf(float f) {
    union { float f; unsigned int u; } v; v.f = f;
    unsigned int r = (v.u + 0x7FFFu + ((v.u >> 16) & 1u)) >> 16;
    return (unsigned short)r;
}
__device__ __forceinline__ float bf2f(unsigned short u) {
    union { unsigned int u; float f; } v; v.u = ((unsigned int)u) << 16;
    return v.f;
}

// async global->LDS, 16 B per lane (dest = wave-uniform base + lane*16)
__device__ __forceinline__ void gl_lds16(const unsigned short* g, unsigned short* l) {
    __builtin_amdgcn_global_load_lds(
        (const __attribute__((address_space(1))) void*)g,
        (__attribute__((address_space(3))) void*)l, 16, 0, 0);
}

// ---------------------------------------------------------------------------
// prep_w: weights fp32 -> bf16 (verbatim).  128 blocks.
// ---------------------------------------------------------------------------
__global__ __launch_bounds__(256) void prep_w(
    const float* __restrict__ wq, const float* __restrict__ wp,
    unsigned short* __restrict__ dwq, unsigned short* __restrict__ dwp)
{
    int ti = blockIdx.x * 256 + threadIdx.x;
    if (ti < 24576) {                       // 3*CC*CC / 8
        int i = ti * 8;
        float4 f0 = ld4(wq + i), f1 = ld4(wq + i + 4);
        v8u o;
        o[0] = f2bf(f0.x); o[1] = f2bf(f0.y); o[2] = f2bf(f0.z); o[3] = f2bf(f0.w);
        o[4] = f2bf(f1.x); o[5] = f2bf(f1.y); o[6] = f2bf(f1.z); o[7] = f2bf(f1.w);
        *(v8u*)(dwq + i) = o;
    } else {                                // CC*CC / 8
        int i = (ti - 24576) * 8;
        float4 f0 = ld4(wp + i), f1 = ld4(wp + i + 4);
        v8u o;
        o[0] = f2bf(f0.x); o[1] = f2bf(f0.y); o[2] = f2bf(f0.z); o[3] = f2bf(f0.w);
        o[4] = f2bf(f1.x); o[5] = f2bf(f1.y); o[6] = f2bf(f1.z); o[7] = f2bf(f1.w);
        *(v8u*)(dwp + i) = o;
    }
}

// ---------------------------------------------------------------------------
// W half-tile prefetch (verbatim R5): 256 j x 32 c into wbuf_b, pre-swizzled
// source so LDS holds chunk (pos ^ swzf(row)) at pos, swzf(row) = (row>>1)&3.
// KEY PROPERTY: wave w stages exactly j-rows [w*64, w*64+64) — the same rows
// its MFMAs read — so W staging is WAVE-PRIVATE: no barrier needed, only a
// per-wave counted vmcnt wait.
// ---------------------------------------------------------------------------
__device__ __forceinline__ void issue_w(
    const unsigned short* __restrict__ wqb, unsigned short* wbuf_b,
    int jt, int kt, int wave, int lane)
{
    const int wrow = lane >> 2;
    const int wsc  = (lane & 3) ^ ((lane >> 3) & 3);
    const unsigned short* wg = wqb + (size_t)(jt * 256 + wave * 64 + wrow) * CC
                             + kt * 32 + wsc * 8;
    unsigned short* wl = wbuf_b + wave * 2048 + lane * 8;
#pragma unroll
    for (int i = 0; i < 4; ++i)
        gl_lds16(wg + (size_t)i * 16 * CC, wl + i * 512);
}

// ---------------------------------------------------------------------------
// Kernel 1: qkv GEMM, barrier-free K-loop.
// Block = one (64 l, n) tile.  X transposed + staged ONCE (full K=256, 32 KB,
// XOR-swizzled) -> single __syncthreads.  24 phases (3 jt x 8 kt, K-step 32)
// with depth-2 W prefetch into wbuf[3] (3 x 16 KB); per phase: issue W(t+2),
// s_waitcnt vmcnt(8) for W(t) (wave-private => no barrier), ds_read + 16 MFMA.
// Buffer reuse distance = 3 phases; safety: phase t-1's ds_reads are lgkmcnt-
// drained before its MFMAs, which precede phase t's gl_lds issue.
// LDS 80 KB -> exactly 2 blocks/CU.  Epilogues verbatim (harness-verified).
// ---------------------------------------------------------------------------
__global__ __launch_bounds__(256, 2) void gemm_qkv_mfma(
    const float* __restrict__ x, const unsigned short* __restrict__ wqb,
    const float* __restrict__ bqkv,
    unsigned short* __restrict__ q, unsigned short* __restrict__ k,
    unsigned short* __restrict__ v, float* __restrict__ attn)
{
    __shared__ __align__(16) unsigned short xsf[16384];     // 64 l x 256 c (swz)
    __shared__ __align__(16) unsigned short wbuf[3][8192];  // 3 x (256 j x 32 c, swz)

    const int bid = blockIdx.x;
    const int l0 = (bid & 63) * 64;
    const int n  = bid >> 6;
    const int tid = threadIdx.x;
    const int lane = tid & 63, wave = tid >> 6;
    const int r = lane & 15, quad = lane >> 4;

    // prefetch W phases 0 and 1; they fetch during the (long) X stage
    issue_w(wqb, wbuf[0], 0, 0, wave, lane);
    issue_w(wqb, wbuf[1], 0, 1, wave, lane);

    // ---- stage X once: transpose-gather fp32 -> bf16, swizzled (verbatim) ----
    {
        const int lx = tid & 63, cq = tid >> 6;
        const float* xcol = x + (size_t)n * CC * LL + l0 + lx;
        unsigned short* xrow = xsf + lx * 256;
#pragma unroll
        for (int i = 0; i < 8; ++i) {
            const float* src = xcol + (size_t)(cq * 8 + i) * 8 * LL;
            float f[8];
#pragma unroll
            for (int j = 0; j < 8; ++j) f[j] = src[(size_t)j * LL];
            v8u o;
#pragma unroll
            for (int j = 0; j < 8; ++j) o[j] = f2bf(f[j]);
            *(v8u*)(xrow + (cq * 8 + (i ^ (lx & 7))) * 8) = o;
        }
    }

    if (bid < 256) attn[bid * 256 + tid] = 0.f;

    __syncthreads();   // xsf visible to all waves (only cross-wave dependency)

    const int jbase = wave * 64;
    v4f acc[4][4];
#pragma unroll
    for (int mi = 0; mi < 4; ++mi)
#pragma unroll
        for (int nj = 0; nj < 4; ++nj) acc[mi][nj] = (v4f)(0.f);

#pragma unroll
    for (int t = 0; t < 24; ++t) {
        if (t < 22)
            issue_w(wqb, wbuf[(t + 2) % 3], (t + 2) >> 3, (t + 2) & 7, wave, lane);

        // wait for W(t) only (wave-private staging): keep t+1, t+2 in flight
        if (t < 22)      asm volatile("s_waitcnt vmcnt(8)" ::: "memory");
        else if (t == 22) asm volatile("s_waitcnt vmcnt(4)" ::: "memory");
        else              asm volatile("s_waitcnt vmcnt(0)" ::: "memory");
        __builtin_amdgcn_sched_barrier(0);

        const int kt = t & 7;
        const int pos = (kt >> 1) * 8 + ((((kt & 1) << 2) + quad) ^ (r & 7));
        v8s b[4];
#pragma unroll
        for (int nj = 0; nj < 4; ++nj)
            b[nj] = *(const v8s*)(xsf + (nj * 16 + r) * 256 + pos * 8);
        const int ws = (quad ^ ((r >> 1) & 3)) * 8;
        v8s a[4];
#pragma unroll
        for (int mi = 0; mi < 4; ++mi)
            a[mi] = *(const v8s*)(wbuf[t % 3] + (jbase + mi * 16 + r) * 32 + ws);
#pragma unroll
        for (int mi = 0; mi < 4; ++mi)
#pragma unroll
            for (int nj = 0; nj < 4; ++nj)
                acc[mi][nj] = __builtin_amdgcn_mfma_f32_16x16x32_bf16(
                    a[mi], b[nj], acc[mi][nj], 0, 0, 0);

        if ((t & 7) == 7) {
            // ---- epilogue for jt = t>>3 (verbatim, harness-verified) ----
            const int jt = t >> 3;
            const int j0 = jt * 256;
            unsigned short* basep = (jt == 0 ? q : (jt == 1 ? k : v));
            float bias[4][4];
#pragma unroll
            for (int mi = 0; mi < 4; ++mi)
                *(float4*)bias[mi] = *(const float4*)(bqkv + j0 + jbase + mi * 16 + quad * 4);

            unsigned short* dstp[4];
#pragma unroll
            for (int mi = 0; mi < 4; ++mi) {
                int hh = wave * 2 + (mi >> 1);
                int d0 = (mi & 1) * 16 + quad * 4;
                dstp[mi] = basep + (size_t)(n * HH + hh) * LL * DD + d0;
            }

            if (jt < 2) {
#pragma unroll
                for (int nj = 0; nj < 4; ++nj) {
                    float t4[4][4];
                    float ss[2] = {0.f, 0.f};
#pragma unroll
                    for (int mi = 0; mi < 4; ++mi)
#pragma unroll
                        for (int reg = 0; reg < 4; ++reg) {
                            float val = acc[mi][nj][reg] + bias[mi][reg];
                            t4[mi][reg] = val;
                            ss[mi >> 1] += val * val;
                        }
#pragma unroll
                    for (int g2 = 0; g2 < 2; ++g2) {
                        ss[g2] += __shfl_xor(ss[g2], 16);
                        ss[g2] += __shfl_xor(ss[g2], 32);
                        ss[g2] = rsqrtf(ss[g2]);
                    }
                    size_t l = (size_t)(l0 + nj * 16 + r);
#pragma unroll
                    for (int mi = 0; mi < 4; ++mi) {
                        float rn = ss[mi >> 1];
                        v4us pk;
#pragma unroll
                        for (int reg = 0; reg < 4; ++reg) pk[reg] = f2bf(t4[mi][reg] * rn);
                        *(v4us*)(dstp[mi] + l * DD) = pk;
                    }
                }
            } else {
#pragma unroll
                for (int nj = 0; nj < 4; ++nj) {
                    size_t l = (size_t)(l0 + nj * 16 + r);
#pragma unroll
                    for (int mi = 0; mi < 4; ++mi) {
                        v4us pk;
#pragma unroll
                        for (int reg = 0; reg < 4; ++reg)
                            pk[reg] = f2bf(acc[mi][nj][reg] + bias[mi][reg]);
                        *(v4us*)(dstp[mi] + l * DD) = pk;
                    }
                }
            }
            // re-zero accumulator for next jt
#pragma unroll
            for (int mi = 0; mi < 4; ++mi)
#pragma unroll
                for (int nj = 0; nj < 4; ++nj) acc[mi][nj] = (v4f)(0.f);
        }
    }
}

// ---------------------------------------------------------------------------
// Kernel 3: attn[n,h,d,e] = sum_l k[n,h,l,d] * v[n,h,l,e]   (verbatim)
// ---------------------------------------------------------------------------
__global__ __launch_bounds__(256) void attn_k(
    const unsigned short* __restrict__ k, const unsigned short* __restrict__ v,
    float* __restrict__ attn)
{
    __shared__ float red[4][1024];
    const int nh = blockIdx.y;
    const int wv = threadIdx.x >> 6;
    const int lane = threadIdx.x & 63;
    const int eg = lane & 7;
    const int dg = lane >> 3;
    const int l0 = blockIdx.x * 512 + wv * 128;
    const unsigned short* kb = k + (size_t)nh * LL * DD;
    const unsigned short* vb = v + (size_t)nh * LL * DD;
    float acc[4][4] = {};
#pragma unroll 4
    for (int l = l0; l < l0 + 128; ++l) {
        v4us k4 = *(const v4us*)(kb + (size_t)l * DD + dg * 4);
        v4us v4 = *(const v4us*)(vb + (size_t)l * DD + eg * 4);
        float ka[4] = {bf2f(k4[0]), bf2f(k4[1]), bf2f(k4[2]), bf2f(k4[3])};
        float va[4] = {bf2f(v4[0]), bf2f(v4[1]), bf2f(v4[2]), bf2f(v4[3])};
#pragma unroll
        for (int dp = 0; dp < 4; ++dp)
#pragma unroll
            for (int ep = 0; ep < 4; ++ep)
                acc[dp][ep] += ka[dp] * va[ep];
    }
#pragma unroll
    for (int dp = 0; dp < 4; ++dp)
#pragma unroll
        for (int ep = 0; ep < 4; ++ep)
            red[wv][(dg * 4 + dp) * 32 + eg * 4 + ep] = acc[dp][ep];
    __syncthreads();
    float* ap = attn + (size_t)nh * 1024;
    for (int i = threadIdx.x; i < 1024; i += 256)
        atomicAdd(&ap[i], red[0][i] + red[1][i] + red[2][i] + red[3][i]);
}

// ---------------------------------------------------------------------------
// Kernel 4 (fused mid + proj): verbatim.
// ---------------------------------------------------------------------------
#define PTOK 64
#define VTP 40
__global__ __launch_bounds__(256, 2) void midproj_k(
    const unsigned short* __restrict__ q, const unsigned short* __restrict__ v,
    const float* __restrict__ attn, const float* __restrict__ wd,
    const unsigned short* __restrict__ wpb, const float* __restrict__ bp,
    float* __restrict__ out)
{
    __shared__ __align__(16) unsigned short vt[8 * 72 * VTP];   // [h][row][40]
    __shared__ __align__(16) unsigned short smid[4 * 64 * 64];  // [chunk][l][64] swz

    const int n  = blockIdx.y;
    const int l0 = blockIdx.x * PTOK;
    const int tid = threadIdx.x;
    const int lane = tid & 63, wave = tid >> 6;
    const int r = lane & 15, quad = lane >> 4;

    // ---- stage v halo for all 8 heads ----
    const unsigned short* vbase = v + (size_t)(n * HH) * LL * DD;
#pragma unroll
    for (int it = 0; it < 9; ++it) {
        int task = it * 256 + tid;            // 2304 = 8h * 72rows * 4segs
        int seg = task & 3;
        int hr = task >> 2;                   // h*72 + row
        int row = hr % 72;
        int h = hr / 72;
        int l = l0 - 4 + row;
        v8u val;
        if (l >= 0 && l < LL)
            val = *(const v8u*)(vbase + ((size_t)h * LL + l) * DD + seg * 8);
        else
            val = (v8u)(unsigned short)0;
        *(v8u*)(&vt[hr * VTP + seg * 8]) = val;
    }
    __syncthreads();

    const float inv_pi = 0.31830988618379067f;
#pragma unroll
    for (int hi = 0; hi < 2; ++hi) {
        const int h = wave * 2 + hi;
        const int nh = n * HH + h;
        const unsigned short* qb = q + (size_t)nh * LL * DD;
        const unsigned short* vth = vt + h * 72 * VTP;

        v8s bfrag[2];
#pragma unroll
        for (int et = 0; et < 2; ++et) {
            int e = et * 16 + r;
#pragma unroll
            for (int j = 0; j < 8; ++j)
                ((unsigned short*)&bfrag[et])[j] =
                    f2bf(attn[(size_t)nh * 1024 + (quad * 8 + j) * 32 + e]);
        }
        float wc[9];
#pragma unroll
        for (int r9 = 0; r9 < 9; ++r9) wc[r9] = wd[h * 9 + r9];

#pragma unroll
        for (int lt = 0; lt < 4; ++lt) {
            const int tb = lt * 16;
            v8s afrag = *(const v8s*)(qb + (size_t)(l0 + tb + r) * DD + quad * 8);
            v4f acc[2] = {(v4f)(0.f), (v4f)(0.f)};
#pragma unroll
            for (int et = 0; et < 2; ++et)
                acc[et] = __builtin_amdgcn_mfma_f32_16x16x32_bf16(
                    afrag, bfrag[et], acc[et], 0, 0, 0);

            float vcol[2][12];
#pragma unroll
            for (int et = 0; et < 2; ++et) {
                int e = et * 16 + r;
#pragma unroll
                for (int o = 0; o < 12; ++o)
                    vcol[et][o] = bf2f(vth[(tb + quad * 4 + o) * VTP + e]);
            }

            float t[2][4], ss[4];
#pragma unroll
            for (int reg = 0; reg < 4; ++reg) {
                t[0][reg] = 0.5f * vcol[0][4 + reg] + inv_pi * acc[0][reg];
                t[1][reg] = 0.5f * vcol[1][4 + reg] + inv_pi * acc[1][reg];
                ss[reg] = t[0][reg] * t[0][reg] + t[1][reg] * t[1][reg];
            }
#pragma unroll
            for (int m = 1; m < 16; m <<= 1)
#pragma unroll
                for (int reg = 0; reg < 4; ++reg)
                    ss[reg] += __shfl_xor(ss[reg], m);
#pragma unroll
            for (int reg = 0; reg < 4; ++reg) ss[reg] = rsqrtf(ss[reg]);

#pragma unroll
            for (int et = 0; et < 2; ++et) {
                int c = h * 32 + et * 16 + r;
                int chunk = c >> 6, c6 = c & 63;
                int goff = c6 & 7;
#pragma unroll
                for (int reg = 0; reg < 4; ++reg) {
                    float dv = 0.f;
#pragma unroll
                    for (int r9 = 0; r9 < 9; ++r9) dv += wc[r9] * vcol[et][reg + r9];
                    int l = tb + quad * 4 + reg;
                    int g = (c6 >> 3) ^ (l & 7);
                    smid[chunk * 4096 + l * 64 + g * 8 + goff] =
                        f2bf(t[et][reg] * ss[reg] + dv);
                }
            }
        }
    }
    __syncthreads();

    // ---- proj phase (no barriers) ----
    const int jbase = wave * 64;
    v4f acc[4][4];
#pragma unroll
    for (int mi = 0; mi < 4; ++mi)
#pragma unroll
        for (int nj = 0; nj < 4; ++nj) acc[mi][nj] = (v4f)(0.f);

#pragma unroll
    for (int kt = 0; kt < 4; ++kt) {
        v8s a[4][2], b[4][2];
#pragma unroll
        for (int kk = 0; kk < 2; ++kk) {
            const int cfrag = kk * 4 + quad;
#pragma unroll
            for (int mi = 0; mi < 4; ++mi) {
                int j = jbase + mi * 16 + r;
                a[mi][kk] = *(const v8s*)(wpb + (size_t)j * CC + kt * 64 + cfrag * 8);
            }
            const int s = cfrag ^ (r & 7);
#pragma unroll
            for (int nj = 0; nj < 4; ++nj) {
                int lloc = nj * 16 + r;
                b[nj][kk] = *(const v8s*)(smid + kt * 4096 + lloc * 64 + s * 8);
            }
        }
#pragma unroll
        for (int kk = 0; kk < 2; ++kk)
#pragma unroll
            for (int mi = 0; mi < 4; ++mi)
#pragma unroll
                for (int nj = 0; nj < 4; ++nj)
                    acc[mi][nj] = __builtin_amdgcn_mfma_f32_16x16x32_bf16(
                        a[mi][kk], b[nj][kk], acc[mi][nj], 0, 0, 0);
    }

#pragma unroll
    for (int mi = 0; mi < 4; ++mi)
#pragma unroll
        for (int reg = 0; reg < 4; ++reg) {
            int j = jbase + mi * 16 + quad * 4 + reg;
            float bias = bp[j];
#pragma unroll
            for (int nj = 0; nj < 4; ++nj) {
                int l = l0 + nj * 16 + r;
                out[((size_t)n * CC + j) * LL + l] = acc[mi][nj][reg] + bias;
            }
        }
}

// ---------------------------------------------------------------------------
extern "C" void kernel_launch(void* const* d_in, const int* in_sizes, int n_in,
                              void* d_out, int out_size, void* d_ws, size_t ws_size,
                              hipStream_t stream)
{
    const float* x     = (const float*)d_in[0];
    const float* wqkv  = (const float*)d_in[1];
    const float* bqkv  = (const float*)d_in[2];
    const float* wproj = (const float*)d_in[3];
    const float* bproj = (const float*)d_in[4];
    const float* wd    = (const float*)d_in[5];
    float* out = (float*)d_out;

    const size_t QKV = (size_t)NB * HH * LL * DD;       // 8388608 elems
    unsigned short* q = (unsigned short*)d_ws;
    unsigned short* k = q + QKV;
    unsigned short* v = k + QKV;
    float* attn = (float*)(v + QKV);                    // 65536 floats
    unsigned short* wqb = (unsigned short*)(attn + (size_t)NB * HH * DD * DD);
    unsigned short* wpb = wqb + 3 * CC * CC;

    prep_w<<<128, 256, 0, stream>>>(wqkv, wproj, wqb, wpb);
    gemm_qkv_mfma<<<512, 256, 0, stream>>>(x, wqb, bqkv, q, k, v, attn);
    attn_k<<<dim3(8, 64), 256, 0, stream>>>(k, v, attn);
    midproj_k<<<dim3(LL / PTOK, NB), 256, 0, stream>>>(q, v, attn, wd, wpb, bproj, out);
}